// Round 7
// baseline (575.500 us; speedup 1.0000x reference)
//
#include <hip/hip_runtime.h>
#include <stdint.h>

typedef float f32x4 __attribute__((ext_vector_type(4)));
typedef float f32x2 __attribute__((ext_vector_type(2)));
typedef short bf16x8 __attribute__((ext_vector_type(8)));
typedef uint32_t u32x4 __attribute__((ext_vector_type(4)));

__device__ __forceinline__ uint32_t bf16_rne(float f) {
  uint32_t x = __float_as_uint(f);
  return (x + 0x7FFFu + ((x >> 16) & 1u)) >> 16;
}

// LDS-only barrier: waits this wave's DS ops, does NOT drain vmcnt.
__device__ __forceinline__ void ldsbar() {
  asm volatile("s_waitcnt lgkmcnt(0)\n\ts_barrier" ::: "memory");
}

// ---------------- kernel 0: cast x (f32) -> bf16 ----------------
__global__ void cast_x_kernel(const float* __restrict__ x,
                              uint32_t* __restrict__ xb, int n2) {
  int i = blockIdx.x * 256 + threadIdx.x;
  if (i >= n2) return;
  f32x2 v = *(const f32x2*)(x + 2 * i);
  xb[i] = bf16_rne(v[0]) | (bf16_rne(v[1]) << 16);
}

// ------------- fully-fused 3-layer MLP, one class per block -------------
// Block = class c, M=256 full batch (8 waves x 32 rows), N processed in
// 8 chunks of 64. W1,W2 each streamed from HBM EXACTLY ONCE (1.34 GB total).
// h1 lives entirely in REGISTERS: h[8][2][2] bf16x8 = 128 VGPR/lane, built
// via a wave-private LDS transpose bounce per chunk. Layer-3 W3-dot fused.
// W stream: 3-deep reg rotation -> v_cvt_pk_bf16_f32 -> swizzled
// ds_write_b128, double-buffered; barriers lgkm-only; vmcnt monotone.
// LDS: 0/8K B-dbuf | 16K b1 | 18K b2 | 20K W3 | 24K b3 | 32K+w*8K transpose.
__global__ __launch_bounds__(512, 2) void fused_mlp(
    const uint16_t* __restrict__ xb, const float* __restrict__ W1,
    const float* __restrict__ b1, const float* __restrict__ W2,
    const float* __restrict__ b2, const float* __restrict__ W3,
    const float* __restrict__ b3, float* __restrict__ out) {
  __shared__ uint8_t smem[98304];

  const int tid = threadIdx.x;
  const int bid = blockIdx.x;
  const int c = ((bid & 7) << 6) | (bid >> 3);  // bijective XCD swizzle

  const float* W1c = W1 + (size_t)c * (768 * 512);
  const float* W2c = W2 + (size_t)c * (512 * 512);

  const int l = tid & 63, w = tid >> 6;
  const int lr = l & 15, lg = l >> 4;

  // stage per-class small tensors (oldest in vmcnt stream)
  ((float*)(smem + 16384))[tid] = b1[(size_t)c * 512 + tid];
  ((float*)(smem + 18432))[tid] = b2[(size_t)c * 512 + tid];
  ((float*)(smem + 20480))[tid] = W3[(size_t)c * 1024 + tid];
  ((float*)(smem + 20480))[tid + 512] = W3[(size_t)c * 1024 + 512 + tid];
  if (tid < 2) ((float*)(smem + 24576))[tid] = b3[c * 2 + tid];

  const uint16_t* Ap = xb + (size_t)(w * 32 + lr) * 768 + lg * 8;
  uint8_t* T = smem + 32768 + w * 8192;  // wave-private transpose tile
  const float* b1s = (const float*)(smem + 16384);
  const float* b2s = (const float*)(smem + 18432);
  const f32x2* w3s = (const f32x2*)(smem + 20480);

  f32x4 acc[2][4];
#pragma unroll
  for (int i = 0; i < 2; i++)
#pragma unroll
    for (int j = 0; j < 4; j++) acc[i][j] = {0.f, 0.f, 0.f, 0.f};

  bf16x8 h[8][2][2];  // [k-chunk][kk][mf] -- all indices static

  auto loadB = [&](const float* Wc, int so, int ts, float* g) {
    const float* p = Wc + (size_t)(ts * 64 + w * 8) * 512 + so * 64 + l;
#pragma unroll
    for (int r = 0; r < 8; r++) g[r] = p[(size_t)r * 512];
  };
  auto loadA = [&](int ts, bf16x8* as) {
#pragma unroll
    for (int kk = 0; kk < 2; ++kk)
#pragma unroll
      for (int mf = 0; mf < 2; mf++)
        as[kk * 2 + mf] =
            *(const bf16x8*)(Ap + ts * 64 + kk * 32 + (size_t)mf * 16 * 768);
  };
  auto writeB = [&](const float* g, int buf) {
    uint32_t p0, p1, p2, p3;
    asm("v_cvt_pk_bf16_f32 %0, %1, %2" : "=v"(p0) : "v"(g[0]), "v"(g[1]));
    asm("v_cvt_pk_bf16_f32 %0, %1, %2" : "=v"(p1) : "v"(g[2]), "v"(g[3]));
    asm("v_cvt_pk_bf16_f32 %0, %1, %2" : "=v"(p2) : "v"(g[4]), "v"(g[5]));
    asm("v_cvt_pk_bf16_f32 %0, %1, %2" : "=v"(p3) : "v"(g[6]), "v"(g[7]));
    u32x4 p = {p0, p1, p2, p3};
    *(u32x4*)(smem + buf * 8192 + l * 128 + ((w ^ (l & 7)) << 4)) = p;
  };
  auto compB = [&](const uint8_t* s, int kk, bf16x8* b) {
    const int kx = ((lg * 16) ^ ((lr & 7) << 4)) ^ (kk << 6);
#pragma unroll
    for (int nf = 0; nf < 4; nf++)
      b[nf] = *(const bf16x8*)(s + (nf * 16 + lr) * 128 + kx);
  };

  float g[3][8];
  bf16x8 a[2][4];

  // =================== layer 1: 8 chunks x 12 K-steps ===================
  loadB(W1c, 0, 0, g[0]);
  loadB(W1c, 0, 1, g[1]);
  loadA(0, a[0]);
  loadB(W1c, 0, 2, g[2]);
  loadA(1, a[1]);
  writeB(g[0], 0);
  ldsbar();

#pragma unroll
  for (int so = 0; so < 8; ++so) {
#pragma unroll
    for (int k = 0; k < 12; ++k) {
      const int t = so * 12 + k;
      {  // comp
        const uint8_t* s = smem + (t & 1) * 8192;
#pragma unroll
        for (int kk = 0; kk < 2; ++kk) {
          bf16x8 b[4];
          compB(s, kk, b);
#pragma unroll
          for (int mf = 0; mf < 2; mf++)
#pragma unroll
            for (int nf = 0; nf < 4; nf++)
              acc[mf][nf] = __builtin_amdgcn_mfma_f32_16x16x32_bf16(
                  a[t & 1][kk * 2 + mf], b[nf], acc[mf][nf], 0, 0, 0);
        }
      }
      if (k == 11) {  // epilogue: bias+relu -> transpose bounce -> h regs
#pragma unroll
        for (int mf = 0; mf < 2; mf++)
#pragma unroll
          for (int nf = 0; nf < 4; nf++) {
            float bv = b1s[so * 64 + nf * 16 + lr];
#pragma unroll
            for (int r = 0; r < 4; r++) {
              int m = mf * 16 + lg * 4 + r;
              float v = fmaxf(acc[mf][nf][r] + bv, 0.f);
              *(uint16_t*)(T + m * 128 +
                           (((nf * 16 + lr) * 2) ^ ((m & 7) << 4))) =
                  (uint16_t)bf16_rne(v);
            }
            acc[mf][nf] = f32x4{0.f, 0.f, 0.f, 0.f};
          }
#pragma unroll
        for (int kk = 0; kk < 2; kk++)
#pragma unroll
          for (int mf = 0; mf < 2; mf++) {
            int m = mf * 16 + lr;
            h[so][kk][mf] = *(const bf16x8*)(
                T + m * 128 + ((kk * 64 + lg * 16) ^ ((m & 7) << 4)));
          }
      }
      const bool last = (t == 95);
      if (!last) writeB(g[(t + 1) % 3], (t + 1) & 1);
      if (t + 2 < 96) loadA((t + 2) % 12, a[t & 1]);
      if (t + 3 < 96) loadB(W1c, (t + 3) / 12, (t + 3) % 12, g[t % 3]);
      if (!last) ldsbar();
    }
  }

  // ============ layer 2 + fused layer 3: 8 chunks x 8 K-steps ============
  float s0[2][4], s1[2][4];
#pragma unroll
  for (int mf = 0; mf < 2; mf++)
#pragma unroll
    for (int r = 0; r < 4; r++) {
      s0[mf][r] = 0.f;
      s1[mf][r] = 0.f;
    }

  loadB(W2c, 0, 0, g[0]);
  loadB(W2c, 0, 1, g[1]);
  loadB(W2c, 0, 2, g[2]);
  writeB(g[0], 0);
  ldsbar();

#pragma unroll
  for (int so = 0; so < 8; ++so) {
#pragma unroll
    for (int k = 0; k < 8; ++k) {
      const int t = so * 8 + k;
      {  // comp: A from h regs
        const uint8_t* s = smem + (t & 1) * 8192;
#pragma unroll
        for (int kk = 0; kk < 2; ++kk) {
          bf16x8 b[4];
          compB(s, kk, b);
#pragma unroll
          for (int mf = 0; mf < 2; mf++)
#pragma unroll
            for (int nf = 0; nf < 4; nf++)
              acc[mf][nf] = __builtin_amdgcn_mfma_f32_16x16x32_bf16(
                  h[k][kk][mf], b[nf], acc[mf][nf], 0, 0, 0);
        }
      }
      if (k == 7) {  // epilogue: bias+relu -> W3 dot accumulate
#pragma unroll
        for (int mf = 0; mf < 2; mf++)
#pragma unroll
          for (int nf = 0; nf < 4; nf++) {
            float bv = b2s[so * 64 + nf * 16 + lr];
            f32x2 wp = w3s[so * 64 + nf * 16 + lr];
#pragma unroll
            for (int r = 0; r < 4; r++) {
              float v = fmaxf(acc[mf][nf][r] + bv, 0.f);
              s0[mf][r] += v * wp[0];
              s1[mf][r] += v * wp[1];
            }
            acc[mf][nf] = f32x4{0.f, 0.f, 0.f, 0.f};
          }
      }
      const bool last = (t == 63);
      if (!last) writeB(g[(t + 1) % 3], (t + 1) & 1);
      if (t + 3 < 64) loadB(W2c, (t + 3) / 8, (t + 3) % 8, g[t % 3]);
      if (!last) ldsbar();
    }
  }

  // ---------------- final: shfl-reduce over 16 lanes, store ----------------
  f32x2 b3v = *(const f32x2*)(smem + 24576);
#pragma unroll
  for (int mf = 0; mf < 2; mf++)
#pragma unroll
    for (int r = 0; r < 4; r++) {
      float t0 = s0[mf][r], t1 = s1[mf][r];
#pragma unroll
      for (int d = 1; d < 16; d <<= 1) {
        t0 += __shfl_xor(t0, d);
        t1 += __shfl_xor(t1, d);
      }
      if (lr == 0) {
        int row = w * 32 + mf * 16 + lg * 4 + r;
        *(f32x2*)(out + ((size_t)row * 512 + c) * 2) =
            f32x2{t0 + b3v[0], t1 + b3v[1]};
      }
    }
}

extern "C" void kernel_launch(void* const* d_in, const int* in_sizes, int n_in,
                              void* d_out, int out_size, void* d_ws,
                              size_t ws_size, hipStream_t stream) {
  const float* x = (const float*)d_in[0];
  const float* W1 = (const float*)d_in[1];
  const float* b1 = (const float*)d_in[2];
  const float* W2 = (const float*)d_in[3];
  const float* b2 = (const float*)d_in[4];
  const float* W3 = (const float*)d_in[5];
  const float* b3 = (const float*)d_in[6];
  float* out = (float*)d_out;

  uint8_t* ws = (uint8_t*)d_ws;
  if (ws_size < 393216) return;
  uint32_t* xb = (uint32_t*)ws;

  cast_x_kernel<<<dim3(384), dim3(256), 0, stream>>>(x, xb, 98304);
  fused_mlp<<<dim3(512), dim3(512), 0, stream>>>(
      (const uint16_t*)xb, W1, b1, W2, b2, W3, b3, out);
}